// Round 12
// baseline (1467.470 us; speedup 1.0000x reference)
//
#include <hip/hip_runtime.h>
#include <hip/hip_fp16.h>

#define N_NODES 100000
#define N_EDGES 1600000
#define NBUCKET 196          // ceil(100000 / 512)
#define CAP     8960         // per-bucket capacity (+8.8 sigma)
#define GRID    1024         // 4 blocks/CU x 256 CUs -- guaranteed co-resident
#define PBLK    (GRID - 20)
#define EPB2    ((N_EDGES + PBLK - 1) / PBLK)   // 1594 edges per partition block
#define NTILES  ((N_NODES + 15) / 16)           // 6250 gemm row-tiles

typedef _Float16 half8 __attribute__((ext_vector_type(8)));
typedef float float4v __attribute__((ext_vector_type(4)));

// ---------------- two-level grid barrier (state in ws, zeroed by memset each call)
// bb layout (ints): flag[p]=bb[p*16]; root[p]=bb[128+p*16]; grp[p][g]=bb[256+p*32+g]
__device__ __forceinline__ void gridbar(int* bb, int phase) {
    __syncthreads();
    if (threadIdx.x == 0) {
        __threadfence();  // release: drain writes past per-XCD L2
        int g = blockIdx.x & 31;                       // 32 groups x 32 blocks
        if (atomicAdd(&bb[256 + phase * 32 + g], 1) == 31) {
            if (atomicAdd(&bb[128 + phase * 16], 1) == 31) {
                __threadfence();
                atomicExch(&bb[phase * 16], 1);        // release flag
            }
        }
        long it = 0;
        while (__hip_atomic_load(&bb[phase * 16], __ATOMIC_ACQUIRE,
                                 __HIP_MEMORY_SCOPE_AGENT) == 0) {
            __builtin_amdgcn_s_sleep(8);
            if (++it > 1000000L) break;   // safety: visible failure, not a hang
        }
        __threadfence();  // acquire: invalidate stale L2
    }
    __syncthreads();
}

// ---------------- MFMA GEMM phase (LDS-W, swapped-D, UNSCALED output)
// out[i][:] = fp16( X[i][:] @ W ); mfma(wf, xf, acc) = D^T: lane (q,m) holds
// 4 contiguous out cols nt*16+q*4 of row m -> direct uint2 stores.
template <int BN, bool AFP16>
__device__ __forceinline__ void gemm_phase(const void* Xv, const _Float16* wsz,
                                           __half* out, _Float16* smem,
                                           int bstart, int bcnt) {
    if ((int)blockIdx.x < bstart) return;   // block-uniform
    const int tid = threadIdx.x;
    for (int i = tid; i < BN * 16; i += 256)
        *(uint4*)&smem[i << 3] = *(const uint4*)&wsz[i << 3];
    __syncthreads();
    const int lane = tid & 63;
    const int q = lane >> 4;
    const int m = lane & 15;
    const int wid = (((int)blockIdx.x - bstart) << 2) + (tid >> 6);
    const int nw = bcnt << 2;
    for (int tile = wid; tile < NTILES; tile += nw) {
        const int arow = tile * 16 + m;
        const int arowc = arow < N_NODES ? arow : N_NODES - 1;
        half8 xf[4];
        if constexpr (AFP16) {
            const _Float16* A = (const _Float16*)Xv + (size_t)arowc * 128 + (q << 3);
#pragma unroll
            for (int kb = 0; kb < 4; ++kb) xf[kb] = *(const half8*)(A + kb * 32);
        } else {
            const float* A = (const float*)Xv + (size_t)arowc * 128 + (q << 3);
#pragma unroll
            for (int kb = 0; kb < 4; ++kb) {
                float4 a0 = *(const float4*)(A + kb * 32);
                float4 a1 = *(const float4*)(A + kb * 32 + 4);
                xf[kb][0] = (_Float16)a0.x; xf[kb][1] = (_Float16)a0.y;
                xf[kb][2] = (_Float16)a0.z; xf[kb][3] = (_Float16)a0.w;
                xf[kb][4] = (_Float16)a1.x; xf[kb][5] = (_Float16)a1.y;
                xf[kb][6] = (_Float16)a1.z; xf[kb][7] = (_Float16)a1.w;
            }
        }
        constexpr int NT = BN / 16;
        float4v acc[NT];
#pragma unroll
        for (int nt = 0; nt < NT; ++nt) acc[nt] = (float4v){0.f, 0.f, 0.f, 0.f};
#pragma unroll
        for (int kb = 0; kb < 4; ++kb)
#pragma unroll
            for (int nt = 0; nt < NT; ++nt) {
                half8 wf = *(const half8*)&smem[(((nt << 2) + kb) << 9) + (lane << 3)];
                acc[nt] = __builtin_amdgcn_mfma_f32_16x16x32_f16(wf, xf[kb], acc[nt], 0, 0, 0);
            }
        if (arow < N_NODES) {
#pragma unroll
            for (int nt = 0; nt < NT; ++nt) {
                _Float16 ov[4];
#pragma unroll
                for (int r = 0; r < 4; ++r) ov[r] = (_Float16)acc[nt][r];
                *(uint2*)&out[(size_t)arow * BN + nt * 16 + q * 4] = *(uint2*)ov;
            }
        }
    }
}

// ---------------- aggregation phase: grid-stride, 4 edges/wave-load, per-edge dinv
// out[i] = act( di * ( sum_j dinv[j]*h[j] + di*h[i] ) + b )
template <int D, bool RELU, typename OT>
__device__ __forceinline__ void agg_phase(const __half* tp, const int* adj,
                                          const int* stv, const int* deg,
                                          const float* dinv, const float* bias,
                                          OT* out) {
    const int w = threadIdx.x >> 6;
    const int lane = threadIdx.x & 63;
    const int g = lane >> 4;
    const int sl = lane & 15;
    constexpr int NA = D / 16;                 // floats per lane chunk: 8 or 4

    for (int node = ((int)blockIdx.x << 2) + w; node < N_NODES; node += GRID * 4) {
        const int s = stv[node];
        const int cnt = deg[node];
        const float di = dinv[node];
        float acc[NA];
#pragma unroll
        for (int i = 0; i < NA; ++i) acc[i] = 0.f;

        auto addrow = [&](float c, const __half2* v) {
#pragma unroll
            for (int i = 0; i < NA / 2; ++i) {
                float2 f = __half22float2(v[i]);
                acc[2 * i] = fmaf(c, f.x, acc[2 * i]);
                acc[2 * i + 1] = fmaf(c, f.y, acc[2 * i + 1]);
            }
        };
        const __half2* base = (const __half2*)tp;
        // self-loop (weight di), group 0 only
        if (g == 0) addrow(di, base + (size_t)node * (D / 2) + sl * (NA / 2));
        int e = 0;
        for (; e + 16 <= cnt; e += 16) {
            int j[4];
#pragma unroll
            for (int u = 0; u < 4; ++u) j[u] = adj[s + e + 4 * u + g];
            float dj[4];
#pragma unroll
            for (int u = 0; u < 4; ++u) dj[u] = dinv[j[u]];
            __half2 v[4][NA / 2];
#pragma unroll
            for (int u = 0; u < 4; ++u)
#pragma unroll
                for (int i = 0; i < NA / 2; ++i)
                    v[u][i] = base[(size_t)j[u] * (D / 2) + sl * (NA / 2) + i];
#pragma unroll
            for (int u = 0; u < 4; ++u) addrow(dj[u], v[u]);
        }
        for (; e + 4 <= cnt; e += 4) {
            int j = adj[s + e + g];
            addrow(dinv[j], base + (size_t)j * (D / 2) + sl * (NA / 2));
        }
        if (e + g < cnt) {
            int j = adj[s + e + g];
            addrow(dinv[j], base + (size_t)j * (D / 2) + sl * (NA / 2));
        }
#pragma unroll
        for (int i = 0; i < NA; ++i) {
            acc[i] += __shfl_xor(acc[i], 32);
            acc[i] += __shfl_xor(acc[i], 16);
        }
        if (g == 0) {
            float o[NA];
#pragma unroll
            for (int i = 0; i < NA; ++i) {
                o[i] = di * acc[i] + bias[sl * NA + i];
                if (RELU) o[i] = fmaxf(o[i], 0.f);
            }
            if constexpr (sizeof(OT) == 2) {
                __half2 ov[NA / 2];
#pragma unroll
                for (int i = 0; i < NA / 2; ++i)
                    ov[i] = __floats2half2_rn(o[2 * i], o[2 * i + 1]);
                if constexpr (NA == 8)
                    *(uint4*)&out[(size_t)node * D + sl * NA] = *(uint4*)ov;
                else
                    *(uint2*)&out[(size_t)node * D + sl * NA] = *(uint2*)ov;
            } else {
#pragma unroll
                for (int i = 0; i < NA; i += 4)
                    *(float4*)&out[(size_t)node * D + sl * NA + i] = *(float4*)&o[i];
            }
        }
    }
}

// ---------------- the mega-kernel: 7 phases, 6 grid barriers, 1 dispatch
__launch_bounds__(256, 4)
__global__ void k_mega(const float* __restrict__ x, const int* __restrict__ src,
                       const int* __restrict__ dst,
                       const float* __restrict__ W1, const float* __restrict__ W2,
                       const float* __restrict__ W3,
                       const float* __restrict__ b1, const float* __restrict__ b2,
                       const float* __restrict__ b3,
                       int* bb, int* bCur, int* ebuf,
                       _Float16* wz1, _Float16* wz2, _Float16* wz3,
                       int* adj, int* stv, int* deg, float* dinv,
                       __half* tp, _Float16* hbuf, float* out) {
    __shared__ __align__(16) _Float16 smem[16384];   // 32 KB, reused per phase
    const int b = blockIdx.x;
    const int tid = threadIdx.x;

    // ================= P0: wswz (blocks 0..19) || partition (blocks 20..1023)
    if (b < 20) {
        int t = b * 256 + tid;
        const float* W; _Float16* wsz; int BN;
        if (t < 2048)      { W = W1; wsz = wz1; BN = 128; }
        else if (t < 4096) { W = W2; wsz = wz2; BN = 128; t -= 2048; }
        else               { W = W3; wsz = wz3; BN = 64;  t -= 4096; }
        const int l = t & 63;
        const int kblk = (t >> 6) & 3;
        const int nt = t >> 8;
        const int krow = kblk * 32 + ((l >> 4) << 3);
        const int col = nt * 16 + (l & 15);
        _Float16 v[8];
#pragma unroll
        for (int j = 0; j < 8; ++j) v[j] = (_Float16)W[(krow + j) * BN + col];
        *(uint4*)&wsz[t << 3] = *(uint4*)v;
    } else {
        int* hist = (int*)smem;            // 256 ints
        int* basebkt = hist + 256;         // 256 ints
        if (tid < 256) hist[tid] = 0;
        __syncthreads();
        const int e0 = (b - 20) * EPB2, e1 = min(e0 + EPB2, N_EDGES);
        for (int e = e0 + tid; e < e1; e += 256) atomicAdd(&hist[dst[e] >> 9], 1);
        __syncthreads();
        if (tid < NBUCKET) {
            int h = hist[tid];
            basebkt[tid] = tid * CAP + (h ? atomicAdd(&bCur[tid], h) : 0);
        }
        __syncthreads();
        if (tid < 256) hist[tid] = 0;
        __syncthreads();
        for (int e = e0 + tid; e < e1; e += 256) {
            int d = dst[e];
            int bk = d >> 9;
            int o = atomicAdd(&hist[bk], 1);
            ebuf[basebkt[bk] + o] = (src[e] << 9) | (d & 511);
        }
    }
    gridbar(bb, 0);

    // ================= P1: bsort (blocks 0..195) || gemm1 (blocks 196..1023)
    if (b < NBUCKET) {
        int* cnt = (int*)smem;             // 512 ints
        int* offs = cnt + 512;             // 512 ints
        const int base = b * CAP;
        const int n_b = min(bCur[b], CAP);
        const int node0 = b << 9;
        cnt[tid] = 0; cnt[tid + 256] = 0;
        __syncthreads();
        for (int i = tid; i < n_b; i += 256)
            atomicAdd(&cnt[ebuf[base + i] & 511], 1);
        __syncthreads();
        if (tid < 64) {
            int v[8], tot = 0;
#pragma unroll
            for (int j = 0; j < 8; ++j) { int t = cnt[tid * 8 + j]; v[j] = tot; tot += t; }
            int inc = tot;
#pragma unroll
            for (int d = 1; d < 64; d <<= 1) {
                int u = __shfl_up(inc, d, 64);
                if (tid >= d) inc += u;
            }
            const int excl = inc - tot;
#pragma unroll
            for (int j = 0; j < 8; ++j) offs[tid * 8 + j] = excl + v[j];
        }
        __syncthreads();
#pragma unroll
        for (int h = 0; h < 2; ++h) {
            int local = tid + h * 256;
            int node = node0 + local;
            if (node < N_NODES) {
                stv[node] = base + offs[local];
                deg[node] = cnt[local];
                dinv[node] = rsqrtf((float)(cnt[local] + 1));
            }
        }
        __syncthreads();
        for (int i = tid; i < n_b; i += 256) {
            int pk = ebuf[base + i];
            int pos = atomicAdd(&offs[pk & 511], 1);
            adj[base + pos] = pk >> 9;
        }
    } else {
        gemm_phase<128, false>(x, wz1, tp, smem, NBUCKET, GRID - NBUCKET);
    }
    gridbar(bb, 1);

    // ================= P2..P6: agg1, gemm2, agg2, gemm3, agg64
    agg_phase<128, true, _Float16>(tp, adj, stv, deg, dinv, b1, hbuf);
    gridbar(bb, 2);
    gemm_phase<128, true>(hbuf, wz2, tp, smem, 0, GRID);
    gridbar(bb, 3);
    agg_phase<128, true, _Float16>(tp, adj, stv, deg, dinv, b2, hbuf);
    gridbar(bb, 4);
    gemm_phase<64, true>(hbuf, wz3, tp, smem, 0, GRID);
    gridbar(bb, 5);
    agg_phase<64, false, float>(tp, adj, stv, deg, dinv, b3, out);
}

extern "C" void kernel_launch(void* const* d_in, const int* in_sizes, int n_in,
                              void* d_out, int out_size, void* d_ws, size_t ws_size,
                              hipStream_t stream) {
    const float* x  = (const float*)d_in[0];
    const int*   ei = (const int*)d_in[1];
    const float* W1 = (const float*)d_in[2];
    const float* b1 = (const float*)d_in[3];
    const float* W2 = (const float*)d_in[4];
    const float* b2 = (const float*)d_in[5];
    const float* W3 = (const float*)d_in[6];
    const float* b3 = (const float*)d_in[7];
    float* out = (float*)d_out;
    const int* src = ei;            // edge_index[0]
    const int* dst = ei + N_EDGES;  // edge_index[1]

    char* p = (char*)d_ws;
    int*  bb   = (int*)p;     p += 2048;                               // barrier state
    int*  bCur = (int*)p;     p += 2048;                               // bucket cursors
    __half* tp      = (__half*)p;    p += (size_t)N_NODES * 128 * 2;   // 25.6 MB
    _Float16* hbuf  = (_Float16*)p;  p += (size_t)N_NODES * 128 * 2;   // 25.6 MB
    int*   deg  = (int*)p;    p += (size_t)N_NODES * 4;
    float* dinv = (float*)p;  p += (size_t)N_NODES * 4;
    int*   stv  = (int*)p;    p += (size_t)N_NODES * 4;
    int*   adj  = (int*)p;    p += (size_t)NBUCKET * CAP * 4 + 16384;  // 7.0 MB
    int*   ebuf = (int*)p;    p += (size_t)NBUCKET * CAP * 4 + 16384;  // 7.0 MB (own region: gemm1 || bsort)
    _Float16* wz1 = (_Float16*)p; p += 16384 * 2;
    _Float16* wz2 = (_Float16*)p; p += 16384 * 2;
    _Float16* wz3 = (_Float16*)p; p += 8192 * 2;
    size_t need = (size_t)(p - (char*)d_ws);
    if (ws_size < need) return;  // visible failure rather than OOB

    hipMemsetAsync(d_ws, 0, 4096, stream);   // zero barrier state + bucket cursors
    k_mega<<<GRID, 256, 0, stream>>>(x, src, dst, W1, W2, W3, b1, b2, b3,
                                     bb, bCur, ebuf, wz1, wz2, wz3,
                                     adj, stv, deg, dinv, tp, hbuf, out);
}